// Round 4
// baseline (304.029 us; speedup 1.0000x reference)
//
#include <hip/hip_runtime.h>
#include <hip/hip_bf16.h>

using bf16 = __hip_bfloat16;
typedef __attribute__((ext_vector_type(8))) short bf16x8;    // 8 bf16 = 4 VGPRs (MFMA A/B frag)
typedef __attribute__((ext_vector_type(4))) float f32x4;
typedef __attribute__((ext_vector_type(16))) float f32x16;   // 32x32 MFMA C/D frag

// async global->LDS, 16B per lane; LDS dest = wave-uniform base + lane*16 (m97/m104)
#define GLL(gp, lp) __builtin_amdgcn_global_load_lds( \
    (const __attribute__((address_space(1))) void*)(gp), \
    (__attribute__((address_space(3))) void*)(lp), 16, 0, 0)

#define BAR()    asm volatile("s_barrier" ::: "memory")
#define WAITV0() asm volatile("s_waitcnt vmcnt(0)" ::: "memory")
// counted DS wait: leave the 6 just-issued frag reads in flight, drain the
// previous phase's 6.  sched_barrier stops MFMA hoisting past it (rule 18).
#define LGKM6()  do { asm volatile("s_waitcnt lgkmcnt(6)" ::: "memory"); \
                      __builtin_amdgcn_sched_barrier(0); } while (0)
#define LGKM0()  do { asm volatile("s_waitcnt lgkmcnt(0)" ::: "memory"); \
                      __builtin_amdgcn_sched_barrier(0); } while (0)

__device__ inline short bfbits(float f) {
  union { bf16 h; short s; } u;
  u.h = __float2bfloat16(f);
  return u.s;
}

__device__ inline bf16x8 ldcvt(const float* __restrict__ g) {
  const float4 f0 = *(const float4*)(g);
  const float4 f1 = *(const float4*)(g + 4);
  union { short s[8]; bf16x8 v; } u;
  u.s[0] = bfbits(f0.x); u.s[1] = bfbits(f0.y); u.s[2] = bfbits(f0.z); u.s[3] = bfbits(f0.w);
  u.s[4] = bfbits(f1.x); u.s[5] = bfbits(f1.y); u.s[6] = bfbits(f1.z); u.s[7] = bfbits(f1.w);
  return u.v;
}

// elementwise fp32 -> bf16, 8 elems/thread
__global__ __launch_bounds__(256)
void f32_to_bf16(const float* __restrict__ src, bf16* __restrict__ dst, int n8) {
  const int i = blockIdx.x * 256 + threadIdx.x;
  if (i < n8) *(bf16x8*)(dst + (size_t)i * 8) = ldcvt(src + (size_t)i * 8);
}

// ---------------------------------------------------------------------------
// 256x256 GEMM, 32x32x16 MFMA, counted-lgkm software pipeline.
// C[m,n] = sum_k A[m*lda+k]*B[n*ldb+k] (+bias[n]).  M,N mult of 256; K mult
// of 128.  Block 512 (8 waves = 2M x 4N, wave tile 128x64 = 4x2 32x32 tiles).
//
// LDS: smem[4][256][64] bf16 = A0|A1|B0|B1, 128 KiB.  T2 swizzle: linear GLL
// dest + pre-swizzled global source column; reads un-permute:
//   LDS[row,chunk] = G[row, chunk ^ (row&7)]  (chunk = 16B unit of the row).
//
// Pipeline: 8 phases/iter (2 K-tiles), each phase = one K=16 slice:
//   {issue NEXT phase's 6 frag reads (a[4]+b[2]); [GLL stage / vmcnt];
//    lgkmcnt(6); 8 MFMA; [barrier]}
// The 6 in-flight ds_reads overlap this phase's MFMAs (the round-2 kernel
// drained lgkm to 0 pre-MFMA -> LDS and MFMA serialized, 39% MfmaUtil).
// Ledger: 12 outstanding pre-wait, 6 post-wait, uniform in every phase.
// Stage/WAR windows (derived): buf1<-kt1 staged @p0, gate vmcnt(0)+bar @p2,
// read @p3..p6, freed by bar @p7.  buf0<-kt+2 staged @p4 (freed by bar @p3),
// gate @p6, read @p7..p2(next).  Barriers only at p2,p3,p6,p7.
// ---------------------------------------------------------------------------
template <typename TC, bool SPLIT3>
__global__ __launch_bounds__(512, 2)
void gemm256(const bf16* __restrict__ A, const bf16* __restrict__ B,
             const float* __restrict__ bias, TC* __restrict__ C,
             int K, int lda, int ldb, int ldc, int nbx) {
  __shared__ __align__(16) bf16 smem[4][256][64];
  char* lds = (char*)&smem[0][0][0];
  const int tid  = threadIdx.x;
  const int lane = tid & 63;
  const int wave = tid >> 6;          // 0..7
  const int wm = wave >> 2;           // 0..1 : rows [wm*128, +128)
  const int wn = wave & 3;            // 0..3 : cols [wn*64, +64)

  // T1: bijective XCD swizzle (nwg % 8 == 0 in all our launches)
  int wg = blockIdx.x;
  const int nwg = gridDim.x;
  if ((nwg & 7) == 0) wg = (wg & 7) * (nwg >> 3) + (wg >> 3);
  const int m0 = (wg / nbx) * 256;
  const int n0 = (wg % nbx) * 256;

  // staging map: lane l of wave w covers LDS row (band + w*8 + (l>>3)),
  // 16B chunk (l&7); global source column pre-swizzled by chunk ^ (row&7).
  const int srow = wave * 8 + (lane >> 3);
  const int scol = ((lane & 7) ^ (lane >> 3)) * 8;
  const bf16* gA = A + (size_t)(m0 + srow) * lda + scol;
  const bf16* gB = B + (size_t)(n0 + srow) * ldb + scol;

  // frag-read addressing (all loop-invariant):
  // A[m-tile][ks]: row = wm*128 + m*32 + r32, chunk = (2*ks+h) ^ (r32&7)
  // B[n-tile][ks]: row = wn*64  + n*32 + r32, same chunk formula
  const int r32 = lane & 31, h = lane >> 5, swz = r32 & 7;
  int aad[4], bad[4];
#pragma unroll
  for (int ks = 0; ks < 4; ++ks) {
    const int ck = (((2 * ks + h) ^ swz) << 4);
    aad[ks] = ((wm * 128 + r32) << 7) + ck;
    bad[ks] = ((wn * 64 + r32) << 7) + 65536 + ck;
  }

#define STAGE_A(buf, kt) do { \
    GLL(gA + (size_t)(  0) * lda + (kt) * 64, lds + (buf) * 32768 + ((  0 + wave * 8) << 7)); \
    GLL(gA + (size_t)( 64) * lda + (kt) * 64, lds + (buf) * 32768 + (( 64 + wave * 8) << 7)); \
    GLL(gA + (size_t)(128) * lda + (kt) * 64, lds + (buf) * 32768 + ((128 + wave * 8) << 7)); \
    GLL(gA + (size_t)(192) * lda + (kt) * 64, lds + (buf) * 32768 + ((192 + wave * 8) << 7)); \
  } while (0)
#define STAGE_B(buf, kt) do { \
    GLL(gB + (size_t)(  0) * ldb + (kt) * 64, lds + 65536 + (buf) * 32768 + ((  0 + wave * 8) << 7)); \
    GLL(gB + (size_t)( 64) * ldb + (kt) * 64, lds + 65536 + (buf) * 32768 + (( 64 + wave * 8) << 7)); \
    GLL(gB + (size_t)(128) * ldb + (kt) * 64, lds + 65536 + (buf) * 32768 + ((128 + wave * 8) << 7)); \
    GLL(gB + (size_t)(192) * ldb + (kt) * 64, lds + 65536 + (buf) * 32768 + ((192 + wave * 8) << 7)); \
  } while (0)
// issue the 6 frag reads for (buf, ks) into frag set X
#define LD6(afX, bfX, buf, ks) do { \
    afX[0] = *(const bf16x8*)(lds + aad[ks] + ((buf) * 32768 +     0)); \
    afX[1] = *(const bf16x8*)(lds + aad[ks] + ((buf) * 32768 +  4096)); \
    afX[2] = *(const bf16x8*)(lds + aad[ks] + ((buf) * 32768 +  8192)); \
    afX[3] = *(const bf16x8*)(lds + aad[ks] + ((buf) * 32768 + 12288)); \
    bfX[0] = *(const bf16x8*)(lds + bad[ks] + ((buf) * 32768 +     0)); \
    bfX[1] = *(const bf16x8*)(lds + bad[ks] + ((buf) * 32768 +  4096)); \
  } while (0)
#define MFMA8(afX, bfX) do { \
    __builtin_amdgcn_s_setprio(1); \
    _Pragma("unroll") \
    for (int m = 0; m < 4; ++m) { _Pragma("unroll") \
      for (int n = 0; n < 2; ++n) \
        acc[m][n] = __builtin_amdgcn_mfma_f32_32x32x16_bf16( \
            afX[m], bfX[n], acc[m][n], 0, 0, 0); } \
    __builtin_amdgcn_s_setprio(0); } while (0)

  f32x16 acc[4][2] = {};
  bf16x8 af0[4], af1[4], bf0[2], bf1[2];

  // prologue: buf0 <- kt0 (8 GLLs), drain, first frag set
  STAGE_A(0, 0); STAGE_B(0, 0);
  WAITV0(); BAR();
  LD6(af0, bf0, 0, 0);

  const int KT = K >> 6;
  const int NI = KT >> 1;
  for (int i = 0; i < NI; ++i) {
    const int kt1 = 2 * i + 1;
    const int ka  = (2 * i + 2 < KT) ? 2 * i + 2 : 0;   // clamped (dummy tail)
    // p0: stage buf1<-kt1 (freed by bar@p7 prev)
    LD6(af1, bf1, 0, 1); STAGE_A(1, kt1); STAGE_B(1, kt1);
    LGKM6(); MFMA8(af0, bf0);
    // p1
    LD6(af0, bf0, 0, 2);
    LGKM6(); MFMA8(af1, bf1);
    // p2: gate buf1 stage (2-phase cover), publish
    LD6(af1, bf1, 0, 3);
    WAITV0(); LGKM6(); MFMA8(af0, bf0); BAR();
    // p3: first buf1 reads; bar frees buf0 for restage
    LD6(af0, bf0, 1, 0);
    LGKM6(); MFMA8(af1, bf1); BAR();
    // p4: stage buf0<-ka
    LD6(af1, bf1, 1, 1); STAGE_A(0, ka); STAGE_B(0, ka);
    LGKM6(); MFMA8(af0, bf0);
    // p5
    LD6(af0, bf0, 1, 2);
    LGKM6(); MFMA8(af1, bf1);
    // p6: gate buf0 stage, publish
    LD6(af1, bf1, 1, 3);
    WAITV0(); LGKM6(); MFMA8(af0, bf0); BAR();
    // p7: first buf0(kt+2) reads; bar frees buf1
    LD6(af0, bf0, 0, 0);
    LGKM6(); MFMA8(af1, bf1); BAR();
  }
  WAITV0(); LGKM0(); BAR();   // drain before LDS reuse by repack epilogue

  // ------------------------------------------------------------------
  // Epilogue: LDS-repack for coalesced wide stores.  Wave-private 16 KiB.
  // 32x32 C/D layout (m74/m101): col = lane&31, row = (r&3)+8*(r>>2)+4*h.
  // ------------------------------------------------------------------
  const int cn0 = n0 + wn * 64;
  float bvv[2];
  bvv[0] = bias ? bias[cn0 + r32] : 0.0f;
  bvv[1] = bias ? bias[cn0 + 32 + r32] : 0.0f;
  char* myc = lds + wave * 16384;

  if constexpr (sizeof(TC) == 2) {
    // bf16: whole 128x64 wave tile = 16 KiB in one pass
#pragma unroll
    for (int m = 0; m < 4; ++m)
#pragma unroll
      for (int n = 0; n < 2; ++n)
#pragma unroll
        for (int r = 0; r < 16; ++r) {
          const int row = m * 32 + (r & 3) + ((r >> 2) << 3) + (h << 2);
          const int col = (n << 5) + r32;
          const int chunk = (col >> 3) ^ (row & 7);
          *(short*)(myc + row * 128 + (chunk << 4) + ((col & 7) << 1)) =
              bfbits(acc[m][n][r] + bvv[n]);
        }
    LGKM0();
    const int rr = lane >> 3, rc = (lane & 7) ^ (lane >> 3);
    size_t cbase;
    if constexpr (SPLIT3)
      cbase = ((size_t)(cn0 >> 10) << 24) + (size_t)(m0 + wm * 128) * 1024 + (cn0 & 1023);
    else
      cbase = (size_t)(m0 + wm * 128) * ldc + cn0;
    const int cstride = SPLIT3 ? 1024 : ldc;
#pragma unroll
    for (int j = 0; j < 16; ++j) {
      const int row = j * 8 + rr;
      const uint4 d = *(const uint4*)(myc + row * 128 + rc * 16);
      *(uint4*)((bf16*)C + cbase + (size_t)row * cstride + (lane & 7) * 8) = d;
    }
  } else {
    // fp32: two 64-row passes of 16 KiB each
#pragma unroll
    for (int p = 0; p < 2; ++p) {
#pragma unroll
      for (int mm = 0; mm < 2; ++mm)
#pragma unroll
        for (int n = 0; n < 2; ++n)
#pragma unroll
          for (int r = 0; r < 16; ++r) {
            const int row = mm * 32 + (r & 3) + ((r >> 2) << 3) + (h << 2);  // 0..63
            const int col = (n << 5) + r32;
            const int chunk = (col >> 2) ^ (row & 7);
            *(float*)(myc + row * 256 + (chunk << 4) + ((col & 3) << 2)) =
                acc[p * 2 + mm][n][r] + bvv[n];
          }
      LGKM0();
      const int rr = lane >> 4, rc0 = lane & 15;
#pragma unroll
      for (int j = 0; j < 16; ++j) {
        const int row = j * 4 + rr;
        const int chunk = rc0 ^ (row & 7);
        const uint4 d = *(const uint4*)(myc + row * 256 + chunk * 16);
        *(uint4*)((float*)C + (size_t)(m0 + wm * 128 + p * 64 + row) * ldc
                  + cn0 + rc0 * 4) = d;
      }
      if (p == 0) LGKM0();   // pass-0 reads done before pass-1 overwrites
    }
  }
#undef STAGE_A
#undef STAGE_B
#undef LD6
#undef MFMA8
}

// Per-token head-attention on plane-packed q/k/v (each 16384 x 1024 bf16).
// One wave per token.  attn result overwrites the q plane.
__global__ __launch_bounds__(256)
void attn_heads(bf16* __restrict__ qp, const bf16* __restrict__ kp,
                const bf16* __restrict__ vp) {
  __shared__ __align__(16) bf16  s_qkv[4][3072];
  __shared__ __align__(16) float s_w[4][256];
  const int lane = threadIdx.x & 63;
  const int wave = threadIdx.x >> 6;
  const size_t tok = (size_t)blockIdx.x * 4 + wave;
  bf16*       qrow = qp + tok * 1024;
  const bf16* krow = kp + tok * 1024;
  const bf16* vrow = vp + tok * 1024;

#pragma unroll
  for (int i = 0; i < 2; ++i) {
    const int off = (i * 64 + lane) * 8;
    *(uint4*)(&s_qkv[wave][off])        = *(const uint4*)(qrow + off);
    *(uint4*)(&s_qkv[wave][1024 + off]) = *(const uint4*)(krow + off);
    *(uint4*)(&s_qkv[wave][2048 + off]) = *(const uint4*)(vrow + off);
  }
  __syncthreads();

  const bf16* sq = s_qkv[wave];
  const int fr   = lane & 15;
  const int quad = lane >> 4;

  f32x4 sc = {0.f, 0.f, 0.f, 0.f};
#pragma unroll
  for (int c = 0; c < 2; ++c) {
    bf16x8 a = *(const bf16x8*)&sq[fr * 64 + c * 32 + quad * 8];
    bf16x8 b = *(const bf16x8*)&sq[1024 + fr * 64 + c * 32 + quad * 8];
    sc = __builtin_amdgcn_mfma_f32_16x16x32_bf16(a, b, sc, 0, 0, 0);
  }

#pragma unroll
  for (int r = 0; r < 4; ++r) {
    float s = sc[r] * 0.03125f;       // 1/sqrt(1024)
    float mx = s;
#pragma unroll
    for (int msk = 1; msk < 16; msk <<= 1) mx = fmaxf(mx, __shfl_xor(mx, msk, 64));
    float e = __expf(s - mx);
    float sum = e;
#pragma unroll
    for (int msk = 1; msk < 16; msk <<= 1) sum += __shfl_xor(sum, msk, 64);
    s_w[wave][(quad * 4 + r) * 16 + fr] = e / sum;
  }
  __syncthreads();

  float vv[16];
#pragma unroll
  for (int g = 0; g < 16; ++g) vv[g] = __bfloat162float(sq[2048 + g * 64 + lane]);
  const float* wrow = s_w[wave];
#pragma unroll
  for (int hh = 0; hh < 16; ++hh) {
    float o = 0.f;
#pragma unroll
    for (int g4 = 0; g4 < 4; ++g4) {
      f32x4 w4 = *(const f32x4*)&wrow[hh * 16 + g4 * 4];
      o += w4.x * vv[g4 * 4 + 0] + w4.y * vv[g4 * 4 + 1] +
           w4.z * vv[g4 * 4 + 2] + w4.w * vv[g4 * 4 + 3];
    }
    qrow[hh * 64 + lane] = __float2bfloat16(o);
  }
}

extern "C" void kernel_launch(void* const* d_in, const int* in_sizes, int n_in,
                              void* d_out, int out_size, void* d_ws, size_t ws_size,
                              hipStream_t stream) {
  const float* x    = (const float*)d_in[0];   // (4,4096,1024) fp32
  const float* Wqkv = (const float*)d_in[1];   // (3072,1024) fp32
  const float* Wo   = (const float*)d_in[2];   // (1024,1024) fp32
  const float* bo   = (const float*)d_in[3];   // (1024,) fp32

  // Workspace (96 MiB): three 32 MiB planes q | k | v, each 16384x1024 bf16.
  bf16* qp = (bf16*)d_ws;
  bf16* kp = qp + ((size_t)1 << 24);
  bf16* vp = qp + ((size_t)2 << 24);

  // d_out doubles as pre-GEMM2 scratch: x_bf16 (32 MiB) + Wqkv_bf16 (6 MiB);
  // both dead before GEMM2 overwrites d_out (in-stream serialization).
  bf16* xb    = (bf16*)d_out;                  // 16,777,216 elems
  bf16* wqkvb = xb + 16777216;                 //  3,145,728 elems

  // 0) one-time fp32 -> bf16 conversions
  f32_to_bf16<<<8192, 256, 0, stream>>>(x, xb, 2097152);
  f32_to_bf16<<<1536, 256, 0, stream>>>(Wqkv, wqkvb, 393216);

  // 1) qkv = xb @ wqkvb^T (M=16384, N=3072, K=1024), plane-routed C write
  gemm256<bf16, true><<<768, 512, 0, stream>>>(
      xb, wqkvb, nullptr, qp, 1024, 1024, 1024, 1024, 12);

  // 2) per-token head attention; attn overwrites the q plane
  attn_heads<<<4096, 256, 0, stream>>>(qp, kp, vp);

  // 3) v plane is dead after attention -> convert Wo into it (2 MiB)
  f32_to_bf16<<<512, 256, 0, stream>>>(Wo, vp, 131072);

  // 4) out = attn @ Wo^T + bo  (M=16384, N=1024, K=1024)
  gemm256<float, false><<<256, 512, 0, stream>>>(
      qp, vp, bo, (float*)d_out, 1024, 1024, 1024, 1024, 4);
}